// Round 9
// baseline (267.644 us; speedup 1.0000x reference)
//
#include <hip/hip_runtime.h>
#include <hip/hip_bf16.h>
#include <math.h>

#define Bsz  2
#define Nseq 1536
#define Dmod 1024
#define NH   16
#define DHd  64
#define MTOT (Bsz*Nseq)          // 3072
#define SCALE 0.125f             // DH^-0.5
#define BK   32

typedef short  short8 __attribute__((ext_vector_type(8)));
typedef float  f32x4  __attribute__((ext_vector_type(4)));
typedef unsigned short u16x4 __attribute__((ext_vector_type(4)));
typedef unsigned short ushortT;

__device__ __forceinline__ float b2f(__hip_bfloat16 v) { return __bfloat162float(v); }
__device__ __forceinline__ unsigned short f2bf(float f) {   // RNE f32->bf16
    union { float f; unsigned u; } a; a.f = f;
    unsigned r = a.u + 0x7fffu + ((a.u >> 16) & 1u);
    return (unsigned short)(r >> 16);
}

// async global->LDS, 16B per lane (wave-uniform base + lane*16)
__device__ __forceinline__ void gl2lds16(const ushortT* g, ushortT* lds) {
    __builtin_amdgcn_global_load_lds(
        (const __attribute__((address_space(1))) unsigned int*)(g),
        (__attribute__((address_space(3))) unsigned int*)(lds),
        16, 0, 0);
}

// ---------------------------------------------------------------------------
// prep: z<5 -> W f32 [k][n] -> Wt bf16 [n][k] transpose;  z==5 -> x f32->bf16
// (grid-stride) + zero gate_logit.
// ---------------------------------------------------------------------------
__global__ __launch_bounds__(256)
void prep_kernel(const float* W0, const float* W1, const float* W2,
                 const float* W3, const float* W4,
                 ushortT* T0, ushortT* T1, ushortT* T2, ushortT* T3, ushortT* T4,
                 const float* __restrict__ x, ushortT* __restrict__ xb,
                 float* __restrict__ glogit)
{
    const int z = blockIdx.z;
    const int t = threadIdx.x;
    if (z == 5) {
        const int bi = blockIdx.y * 16 + blockIdx.x;   // 0..255
        const size_t NEl = (size_t)MTOT * Dmod;
        for (size_t i = ((size_t)bi * 256 + t) * 4; i < NEl; i += (size_t)256 * 256 * 4) {
            float4 v = *(const float4*)(x + i);
            u16x4 o = { f2bf(v.x), f2bf(v.y), f2bf(v.z), f2bf(v.w) };
            *(u16x4*)(xb + i) = o;
        }
        if (t < 12) glogit[bi * 12 + t] = 0.f;
        return;
    }
    __shared__ float tile[64][65];
    const float* W = z == 0 ? W0 : z == 1 ? W1 : z == 2 ? W2 : z == 3 ? W3 : W4;
    ushortT*     T = z == 0 ? T0 : z == 1 ? T1 : z == 2 ? T2 : z == 3 ? T3 : T4;
    const int k0 = blockIdx.x * 64, n0 = blockIdx.y * 64;
    for (int i = t; i < 4096; i += 256) {
        int r = i >> 6, c = i & 63;
        tile[r][c] = W[(size_t)(k0 + r) * 1024 + n0 + c];
    }
    __syncthreads();
    for (int i = t; i < 4096; i += 256) {
        int rn = i >> 6, ck = i & 63;
        T[(size_t)(n0 + rn) * 1024 + k0 + ck] = f2bf(tile[ck][rn]);
    }
}

// ---------------------------------------------------------------------------
// 128x128 MFMA core, BK=32, ping-pong LDS, ONE barrier per K-iter,
// 16 MFMA per barrier.  LDS 32 KB.  4 waves, each 64x64 (4x4 tiles).
// ---------------------------------------------------------------------------
__device__ __forceinline__
void gemm_core128(const ushortT* __restrict__ A, const ushortT* __restrict__ Bt,
                  int m0, int n0, ushortT* As, ushortT* Bs, f32x4 (&acc)[4][4])
{
    const int t = threadIdx.x;
    const int l = t & 63, w = t >> 6;
    const int wm = (w >> 1) * 64, wn = (w & 1) * 64;
    const int lm = l & 15, q = l >> 4;

    const int r0 = t >> 2, c0 = (t & 3) * 8;
    const ushortT* Ag0 = A  + (size_t)(m0 + r0) * 1024 + c0;
    const ushortT* Ag1 = Ag0 + (size_t)64 * 1024;
    const ushortT* Bg0 = Bt + (size_t)(n0 + r0) * 1024 + c0;
    const ushortT* Bg1 = Bg0 + (size_t)64 * 1024;
    ushortT* La0 = As + t * 8;
    ushortT* La1 = As + 2048 + t * 8;
    ushortT* Lb0 = Bs + t * 8;
    ushortT* Lb1 = Bs + 2048 + t * 8;

    gl2lds16(Ag0, La0);
    gl2lds16(Ag1, La1);
    gl2lds16(Bg0, Lb0);
    gl2lds16(Bg1, Lb1);

    for (int kt = 0; kt < 1024 / BK; ++kt) {
        __syncthreads();   // buf[kt&1] loads landed; prev ds_reads done
        if (kt + 1 < 1024 / BK) {
            int ko = (kt + 1) * BK;
            int bo = ((kt + 1) & 1) ? 4096 : 0;
            gl2lds16(Ag0 + ko, La0 + bo);
            gl2lds16(Ag1 + ko, La1 + bo);
            gl2lds16(Bg0 + ko, Lb0 + bo);
            gl2lds16(Bg1 + ko, Lb1 + bo);
        }
        const ushortT* Ab = As + ((kt & 1) ? 4096 : 0);
        const ushortT* Bb = Bs + ((kt & 1) ? 4096 : 0);
        short8 af[4], bf[4];
#pragma unroll
        for (int i = 0; i < 4; ++i) {
            af[i] = *(const short8*)&Ab[(wm + i * 16 + lm) * 32 + q * 8];
            bf[i] = *(const short8*)&Bb[(wn + i * 16 + lm) * 32 + q * 8];
        }
#pragma unroll
        for (int i = 0; i < 4; ++i)
#pragma unroll
            for (int j = 0; j < 4; ++j)
                acc[i][j] = __builtin_amdgcn_mfma_f32_16x16x32_bf16(af[i], bf[j], acc[i][j], 0, 0, 0);
    }
}

// 128x64 core (R8, verified) for gemm_out where block count matters.
__device__ __forceinline__
void gemm_core64(const ushortT* __restrict__ A, const ushortT* __restrict__ Bt,
                 int m0, int n0, ushortT* As, ushortT* Bs, f32x4 (&acc)[4][2])
{
    const int t = threadIdx.x;
    const int l = t & 63, w = t >> 6;
    const int wm = (w >> 1) * 64, wn = (w & 1) * 32;
    const int lm = l & 15, q = l >> 4;

    const int r0 = t >> 2, c0 = (t & 3) * 8;
    const ushortT* Ag0 = A  + (size_t)(m0 + r0) * 1024 + c0;
    const ushortT* Ag1 = Ag0 + (size_t)64 * 1024;
    const ushortT* Bg0 = Bt + (size_t)(n0 + r0) * 1024 + c0;
    ushortT* La0 = As + t * 8;
    ushortT* La1 = As + 2048 + t * 8;
    ushortT* Lb0 = Bs + t * 8;

    gl2lds16(Ag0, La0);
    gl2lds16(Ag1, La1);
    gl2lds16(Bg0, Lb0);

    for (int kt = 0; kt < 1024 / BK; ++kt) {
        __syncthreads();
        if (kt + 1 < 1024 / BK) {
            int ko = (kt + 1) * BK;
            int bo = ((kt + 1) & 1) ? 4096 : 0;
            int bo2 = ((kt + 1) & 1) ? 2048 : 0;
            gl2lds16(Ag0 + ko, La0 + bo);
            gl2lds16(Ag1 + ko, La1 + bo);
            gl2lds16(Bg0 + ko, Lb0 + bo2);
        }
        const ushortT* Ab = As + ((kt & 1) ? 4096 : 0);
        const ushortT* Bb = Bs + ((kt & 1) ? 2048 : 0);
        short8 af[4], bf[2];
#pragma unroll
        for (int i = 0; i < 4; ++i)
            af[i] = *(const short8*)&Ab[(wm + i * 16 + lm) * 32 + q * 8];
#pragma unroll
        for (int j = 0; j < 2; ++j)
            bf[j] = *(const short8*)&Bb[(wn + j * 16 + lm) * 32 + q * 8];
#pragma unroll
        for (int i = 0; i < 4; ++i)
#pragma unroll
            for (int j = 0; j < 2; ++j)
                acc[i][j] = __builtin_amdgcn_mfma_f32_16x16x32_bf16(af[i], bf[j], acc[i][j], 0, 0, 0);
    }
}

// Fused Q/K/V + gate-logit: grid (8,24,4), 128x128 tiles.
// z==0: SCALE folded into Q.  z==2: V stored transposed Vt[b,h,d,N].
// z==3: no store; gelu -> dot with Wg2 -> atomicAdd into glogit[m].
__global__ __launch_bounds__(256)
void gemm_qkvg(const ushortT* __restrict__ xb,
               const ushortT* Wt0, const ushortT* Wt1, const ushortT* Wt2, const ushortT* Wt3,
               const float* bz0, const float* bz1, const float* bz2, const float* bz3,
               const float* __restrict__ Wg2,
               ushortT* O0, ushortT* O1, ushortT* O2, float* __restrict__ glogit)
{
    __shared__ ushortT As[2 * 128 * 32];
    __shared__ ushortT Bs[2 * 128 * 32];
    const int z = blockIdx.z;
    const ushortT* Wt  = z == 0 ? Wt0 : z == 1 ? Wt1 : z == 2 ? Wt2 : Wt3;
    const float*  bias = z == 0 ? bz0 : z == 1 ? bz1 : z == 2 ? bz2 : bz3;
    const int m0 = blockIdx.y * 128, n0 = blockIdx.x * 128;

    f32x4 acc[4][4] = {};
    gemm_core128(xb, Wt, m0, n0, As, Bs, acc);

    const int t = threadIdx.x, l = t & 63, w = t >> 6;
    const int wm = (w >> 1) * 64, wn = (w & 1) * 64;
    const int lm = l & 15, q = l >> 4;

    if (z == 3) {
        float part[4][4] = {};
#pragma unroll
        for (int i = 0; i < 4; ++i)
#pragma unroll
            for (int j = 0; j < 4; ++j) {
                int n = n0 + wn + j * 16 + lm;
                float bn = bias[n];
                float w2 = Wg2[n];
#pragma unroll
                for (int r = 0; r < 4; ++r) {
                    float v = acc[i][j][r] + bn;
                    v = 0.5f * v * (1.0f + erff(v * 0.70710678118654752f));
                    part[i][r] += v * w2;
                }
            }
#pragma unroll
        for (int i = 0; i < 4; ++i)
#pragma unroll
            for (int r = 0; r < 4; ++r) {
                float p = part[i][r];
#pragma unroll
                for (int msk = 1; msk < 16; msk <<= 1) p += __shfl_xor(p, msk, 16);
                if (lm == 0)
                    atomicAdd(&glogit[m0 + wm + i * 16 + q * 4 + r], p);
            }
        return;
    }

    ushortT* O = z == 0 ? O0 : z == 1 ? O1 : O2;
#pragma unroll
    for (int i = 0; i < 4; ++i)
#pragma unroll
        for (int j = 0; j < 4; ++j) {
            int n = n0 + wn + j * 16 + lm;
            float bn = bias[n];
#pragma unroll
            for (int r = 0; r < 4; ++r) {
                int m = m0 + wm + i * 16 + q * 4 + r;
                float v = acc[i][j][r] + bn;
                if (z == 0) v *= SCALE;
                if (z == 2) {  // Vt[((b*16+h)*64+dd)*1536 + nn]
                    int b = m / Nseq, nn = m - b * Nseq;
                    int h = n >> 6, dd = n & 63;
                    O[(size_t)((b * 16 + h) * 64 + dd) * Nseq + nn] = f2bf(v);
                } else {
                    O[(size_t)m * 1024 + n] = f2bf(v);
                }
            }
        }
}

// Output projection: AO bf16 @ WoT -> f32 out.  grid (16,24), 128x64 tiles.
__global__ __launch_bounds__(256)
void gemm_out(const ushortT* __restrict__ AO, const ushortT* __restrict__ WtO,
              const float* __restrict__ bias, float* __restrict__ C)
{
    __shared__ ushortT As[2 * 128 * 32];
    __shared__ ushortT Bs[2 * 64 * 32];
    const int m0 = blockIdx.y * 128, n0 = blockIdx.x * 64;

    f32x4 acc[4][2] = {};
    gemm_core64(AO, WtO, m0, n0, As, Bs, acc);

    const int t = threadIdx.x, l = t & 63, w = t >> 6;
    const int wm = (w >> 1) * 64, wn = (w & 1) * 32;
    const int lm = l & 15, q = l >> 4;
#pragma unroll
    for (int i = 0; i < 4; ++i)
#pragma unroll
        for (int j = 0; j < 2; ++j) {
            int n = n0 + wn + j * 16 + lm;
            float bn = bias[n];
#pragma unroll
            for (int r = 0; r < 4; ++r) {
                int m = m0 + wm + i * 16 + q * 4 + r;
                C[(size_t)m * 1024 + n] = acc[i][j][r] + bn;
            }
        }
}

// ---------------------------------------------------------------------------
// MFMA flash attention: 2 waves/block split the KEY dimension (parity-
// interleaved 64-key tiles; diagonal owned by parity-matching wave).  With
// m==0 (no max tracking) partial (l,t,O) over disjoint key sets sum exactly;
// merged once through LDS in the epilogue.  32 q-rows per block.
// ---------------------------------------------------------------------------
__global__ __launch_bounds__(128)
void attn_mfma(const ushortT* __restrict__ Q, const ushortT* __restrict__ K,
               const ushortT* __restrict__ Vt, const float* __restrict__ glogit,
               const float* __restrict__ bg2, ushortT* __restrict__ AO,
               float* __restrict__ ent)
{
    __shared__ ushortT Ps[2][32][72];
    __shared__ float mbuf[3072];        // 2048 oacc + 512 l + 512 t

    const int t  = threadIdx.x;
    const int w  = t >> 6, l = t & 63;
    const int ln = l & 15, q4 = l >> 4;
    const int bh = blockIdx.x, b = bh >> 4, h = bh & 15;
    const int q32 = (int)gridDim.y - 1 - (int)blockIdx.y;   // big-first
    const int wq = q32 * 32;
    const int kd = wq >> 6;                       // diagonal 64-key tile
    const int sbmax = ((wq >> 4) & 3) + 1;

    const ushortT* Qp = Q + (size_t)(b * Nseq + wq + ln) * Dmod + h * DHd + q4 * 8;
    short8 qf[2][2];
    qf[0][0] = *(const short8*)(Qp);
    qf[0][1] = *(const short8*)(Qp + 32);
    qf[1][0] = *(const short8*)(Qp + (size_t)16 * Dmod);
    qf[1][1] = *(const short8*)(Qp + (size_t)16 * Dmod + 32);

    float l_lane[2][4] = {}, t_lane[2][4] = {};
    f32x4 oacc[2][4] = {};

    const ushortT* Kbase = K  + (size_t)(b * Nseq) * Dmod + h * DHd + q4 * 8;
    const ushortT* Vbase = Vt + ((size_t)(b * 16 + h) * 64) * Nseq + q4 * 8;

    // preload K tile index w
    short8 kc[4][2];
    {
        const ushortT* Kp = Kbase + (size_t)(w * 64 + ln) * Dmod;
#pragma unroll
        for (int nb = 0; nb < 4; ++nb) {
            kc[nb][0] = *(const short8*)(Kp + (size_t)nb * 16 * Dmod);
            kc[nb][1] = *(const short8*)(Kp + (size_t)nb * 16 * Dmod + 32);
        }
    }

    for (int kt = w; kt < kd; kt += 2) {
        const int k0 = kt * 64;
        const ushortT* Vp = Vbase + (size_t)ln * Nseq + k0;
        short8 vf[4][2];
#pragma unroll
        for (int nb = 0; nb < 4; ++nb) {
            vf[nb][0] = *(const short8*)(Vp + (size_t)nb * 16 * Nseq);
            vf[nb][1] = *(const short8*)(Vp + (size_t)nb * 16 * Nseq + 32);
        }
        // prefetch K tile kt+2 (row-clamped; tail value unused)
        short8 kn[4][2];
        {
            int prow = k0 + 128; if (prow > Nseq - 64) prow = Nseq - 64;
            const ushortT* Kp = Kbase + (size_t)(prow + ln) * Dmod;
#pragma unroll
            for (int nb = 0; nb < 4; ++nb) {
                kn[nb][0] = *(const short8*)(Kp + (size_t)nb * 16 * Dmod);
                kn[nb][1] = *(const short8*)(Kp + (size_t)nb * 16 * Dmod + 32);
            }
        }
        f32x4 sacc[2][4];
#pragma unroll
        for (int g = 0; g < 2; ++g)
#pragma unroll
            for (int nb = 0; nb < 4; ++nb) {
                f32x4 a = {};
                a = __builtin_amdgcn_mfma_f32_16x16x32_bf16(qf[g][0], kc[nb][0], a, 0, 0, 0);
                a = __builtin_amdgcn_mfma_f32_16x16x32_bf16(qf[g][1], kc[nb][1], a, 0, 0, 0);
                sacc[g][nb] = a;
            }
#pragma unroll
        for (int g = 0; g < 2; ++g)
#pragma unroll
            for (int nb = 0; nb < 4; ++nb)
#pragma unroll
                for (int r = 0; r < 4; ++r) {
                    float sv = sacc[g][nb][r];
                    float ev = __expf(sv);
                    l_lane[g][r] += ev;
                    t_lane[g][r] += ev * sv;
                    Ps[w][g * 16 + q4 * 4 + r][nb * 16 + ln] = f2bf(ev);
                }
        short8 pf[2][2];
#pragma unroll
        for (int g = 0; g < 2; ++g) {
            pf[g][0] = *(const short8*)&Ps[w][g * 16 + ln][q4 * 8];
            pf[g][1] = *(const short8*)&Ps[w][g * 16 + ln][32 + q4 * 8];
        }
#pragma unroll
        for (int g = 0; g < 2; ++g)
#pragma unroll
            for (int nb = 0; nb < 4; ++nb) {
                oacc[g][nb] = __builtin_amdgcn_mfma_f32_16x16x32_bf16(pf[g][0], vf[nb][0], oacc[g][nb], 0, 0, 0);
                oacc[g][nb] = __builtin_amdgcn_mfma_f32_16x16x32_bf16(pf[g][1], vf[nb][1], oacc[g][nb], 0, 0, 0);
            }
#pragma unroll
        for (int nb = 0; nb < 4; ++nb) { kc[nb][0] = kn[nb][0]; kc[nb][1] = kn[nb][1]; }
    }

    // ---- diagonal tile: owned by the wave whose parity matches kd ----
    if ((kd & 1) == w) {
        const int k0 = kd * 64;
        const ushortT* Vp = Vbase + (size_t)ln * Nseq + k0;
        short8 vf[4][2];
#pragma unroll
        for (int nb = 0; nb < 4; ++nb) {
            vf[nb][0] = *(const short8*)(Vp + (size_t)nb * 16 * Nseq);
            vf[nb][1] = *(const short8*)(Vp + (size_t)nb * 16 * Nseq + 32);
        }
        f32x4 sacc[2][4];
#pragma unroll
        for (int g = 0; g < 2; ++g)
#pragma unroll
            for (int nb = 0; nb < 4; ++nb)
                if (nb <= sbmax) {
                    f32x4 a = {};
                    a = __builtin_amdgcn_mfma_f32_16x16x32_bf16(qf[g][0], kc[nb][0], a, 0, 0, 0);
                    a = __builtin_amdgcn_mfma_f32_16x16x32_bf16(qf[g][1], kc[nb][1], a, 0, 0, 0);
                    sacc[g][nb] = a;
                }
#pragma unroll
        for (int g = 0; g < 2; ++g)
#pragma unroll
            for (int nb = 0; nb < 4; ++nb)
#pragma unroll
                for (int r = 0; r < 4; ++r) {
                    float ev = 0.f;
                    if (nb <= sbmax) {
                        int kg = k0 + nb * 16 + ln;
                        int qg = wq + g * 16 + q4 * 4 + r;
                        float sv = sacc[g][nb][r];
                        ev = (kg <= qg) ? __expf(sv) : 0.f;
                        l_lane[g][r] += ev;
                        t_lane[g][r] += ev * sv;
                    }
                    Ps[w][g * 16 + q4 * 4 + r][nb * 16 + ln] = f2bf(ev);
                }
        short8 pf[2][2];
#pragma unroll
        for (int g = 0; g < 2; ++g) {
            pf[g][0] = *(const short8*)&Ps[w][g * 16 + ln][q4 * 8];
            pf[g][1] = *(const short8*)&Ps[w][g * 16 + ln][32 + q4 * 8];
        }
#pragma unroll
        for (int g = 0; g < 2; ++g)
#pragma unroll
            for (int nb = 0; nb < 4; ++nb) {
                oacc[g][nb] = __builtin_amdgcn_mfma_f32_16x16x32_bf16(pf[g][0], vf[nb][0], oacc[g][nb], 0, 0, 0);
                oacc[g][nb] = __builtin_amdgcn_mfma_f32_16x16x32_bf16(pf[g][1], vf[nb][1], oacc[g][nb], 0, 0, 0);
            }
    }

    // ---- merge wave1 partials into wave0 (exact: disjoint key sets, m==0) ----
    if (w == 1) {
#pragma unroll
        for (int g = 0; g < 2; ++g)
#pragma unroll
            for (int nb = 0; nb < 4; ++nb)
#pragma unroll
                for (int r = 0; r < 4; ++r)
                    mbuf[(((g << 2) | nb) * 4 + r) * 64 + l] = oacc[g][nb][r];
#pragma unroll
        for (int g = 0; g < 2; ++g)
#pragma unroll
            for (int r = 0; r < 4; ++r) {
                mbuf[2048 + ((g << 2) | r) * 64 + l] = l_lane[g][r];
                mbuf[2560 + ((g << 2) | r) * 64 + l] = t_lane[g][r];
            }
    }
    __syncthreads();
    if (w == 1) return;
#pragma unroll
    for (int g = 0; g < 2; ++g) {
#pragma unroll
        for (int nb = 0; nb < 4; ++nb)
#pragma unroll
            for (int r = 0; r < 4; ++r)
                oacc[g][nb][r] += mbuf[(((g << 2) | nb) * 4 + r) * 64 + l];
#pragma unroll
        for (int r = 0; r < 4; ++r) {
            l_lane[g][r] += mbuf[2048 + ((g << 2) | r) * 64 + l];
            t_lane[g][r] += mbuf[2560 + ((g << 2) | r) * 64 + l];
        }
    }

    // ---- epilogue (wave 0 only) ----
    const float bg2v = bg2[0];
#pragma unroll
    for (int g = 0; g < 2; ++g) {
        float sc[4];
#pragma unroll
        for (int r = 0; r < 4; ++r) {
            float lv = l_lane[g][r], tv = t_lane[g][r];
#pragma unroll
            for (int msk = 1; msk < 16; msk <<= 1) {
                lv += __shfl_xor(lv, msk, 16);
                tv += __shfl_xor(tv, msk, 16);
            }
            int qg = wq + g * 16 + q4 * 4 + r;
            float inv = 1.f / lv;
            if (ln == 0)
                ent[((size_t)b * NH + h) * Nseq + qg] = logf(lv) - tv * inv;
            float logit = glogit[b * Nseq + qg] + bg2v;
            sc[r] = inv / (1.f + __expf(-logit));
        }
#pragma unroll
        for (int nb = 0; nb < 4; ++nb)
#pragma unroll
            for (int r = 0; r < 4; ++r) {
                int qg = wq + g * 16 + q4 * 4 + r;
                AO[(size_t)(b * Nseq + qg) * Dmod + h * DHd + nb * 16 + ln] =
                    f2bf(oacc[g][nb][r] * sc[r]);
            }
    }
}

// ---------------------------------------------------------------------------
extern "C" void kernel_launch(void* const* d_in, const int* in_sizes, int n_in,
                              void* d_out, int out_size, void* d_ws, size_t ws_size,
                              hipStream_t stream)
{
    const float* x   = (const float*)d_in[0];
    const float* Wq  = (const float*)d_in[2];
    const float* bq  = (const float*)d_in[3];
    const float* Wk  = (const float*)d_in[4];
    const float* bk  = (const float*)d_in[5];
    const float* Wv  = (const float*)d_in[6];
    const float* bv  = (const float*)d_in[7];
    const float* Wg1 = (const float*)d_in[8];
    const float* bg1 = (const float*)d_in[9];
    const float* Wg2 = (const float*)d_in[10];
    const float* bg2 = (const float*)d_in[11];
    const float* Wo  = (const float*)d_in[12];
    const float* bo  = (const float*)d_in[13];

    const size_t NE = (size_t)MTOT * Dmod;
    ushortT* p   = (ushortT*)d_ws;
    ushortT* Qw  = p; p += NE;
    ushortT* Kw  = p; p += NE;
    ushortT* Vtw = p; p += NE;       // V transposed: [B,H,64,Nseq]
    ushortT* AO  = p; p += NE;
    ushortT* xb  = p; p += NE;
    ushortT* WtQ = p; p += (size_t)1024 * 1024;
    ushortT* WtK = p; p += (size_t)1024 * 1024;
    ushortT* WtV = p; p += (size_t)1024 * 1024;
    ushortT* WtG = p; p += (size_t)1024 * 1024;
    ushortT* WtO = p; p += (size_t)1024 * 1024;
    float* glogit = (float*)p;       // MTOT floats

    float* out_f = (float*)d_out;
    float* ent_f = out_f + NE;

    prep_kernel<<<dim3(16, 16, 6), 256, 0, stream>>>(Wq, Wk, Wv, Wg1, Wo,
                                                     WtQ, WtK, WtV, WtG, WtO,
                                                     x, xb, glogit);
    gemm_qkvg<<<dim3(8, 24, 4), 256, 0, stream>>>(xb, WtQ, WtK, WtV, WtG,
                                                  bq, bk, bv, bg1, Wg2,
                                                  Qw, Kw, Vtw, glogit);
    attn_mfma<<<dim3(Bsz * NH, Nseq / 32), 128, 0, stream>>>(Qw, Kw, Vtw, glogit,
                                                             bg2, AO, ent_f);
    gemm_out<<<dim3(16, 24), 256, 0, stream>>>(AO, WtO, bo, out_f);
}

// Round 10
// 230.067 us; speedup vs baseline: 1.1633x; 1.1633x over previous
//
#include <hip/hip_runtime.h>
#include <hip/hip_bf16.h>
#include <math.h>

#define Bsz  2
#define Nseq 1536
#define Dmod 1024
#define NH   16
#define DHd  64
#define MTOT (Bsz*Nseq)          // 3072
#define SCALE 0.125f             // DH^-0.5
#define BK   32

typedef short  short8 __attribute__((ext_vector_type(8)));
typedef float  f32x4  __attribute__((ext_vector_type(4)));
typedef unsigned short u16x4 __attribute__((ext_vector_type(4)));
typedef unsigned short ushortT;

__device__ __forceinline__ float b2f(__hip_bfloat16 v) { return __bfloat162float(v); }
__device__ __forceinline__ unsigned short f2bf(float f) {   // RNE f32->bf16
    union { float f; unsigned u; } a; a.f = f;
    unsigned r = a.u + 0x7fffu + ((a.u >> 16) & 1u);
    return (unsigned short)(r >> 16);
}

// async global->LDS, 16B per lane (wave-uniform base + lane*16)
__device__ __forceinline__ void gl2lds16(const ushortT* g, ushortT* lds) {
    __builtin_amdgcn_global_load_lds(
        (const __attribute__((address_space(1))) unsigned int*)(g),
        (__attribute__((address_space(3))) unsigned int*)(lds),
        16, 0, 0);
}

// ---------------------------------------------------------------------------
// prep: z<5 -> W f32 [k][n] -> Wt bf16 [n][k] transpose;  z==5 -> x f32->bf16
// (grid-stride) + zero gate_logit.
// ---------------------------------------------------------------------------
__global__ __launch_bounds__(256)
void prep_kernel(const float* W0, const float* W1, const float* W2,
                 const float* W3, const float* W4,
                 ushortT* T0, ushortT* T1, ushortT* T2, ushortT* T3, ushortT* T4,
                 const float* __restrict__ x, ushortT* __restrict__ xb,
                 float* __restrict__ glogit)
{
    const int z = blockIdx.z;
    const int t = threadIdx.x;
    if (z == 5) {
        const int bi = blockIdx.y * 16 + blockIdx.x;   // 0..255
        const size_t NEl = (size_t)MTOT * Dmod;
        for (size_t i = ((size_t)bi * 256 + t) * 4; i < NEl; i += (size_t)256 * 256 * 4) {
            float4 v = *(const float4*)(x + i);
            u16x4 o = { f2bf(v.x), f2bf(v.y), f2bf(v.z), f2bf(v.w) };
            *(u16x4*)(xb + i) = o;
        }
        if (t < 12) glogit[bi * 12 + t] = 0.f;
        return;
    }
    __shared__ float tile[64][65];
    const float* W = z == 0 ? W0 : z == 1 ? W1 : z == 2 ? W2 : z == 3 ? W3 : W4;
    ushortT*     T = z == 0 ? T0 : z == 1 ? T1 : z == 2 ? T2 : z == 3 ? T3 : T4;
    const int k0 = blockIdx.x * 64, n0 = blockIdx.y * 64;
    for (int i = t; i < 4096; i += 256) {
        int r = i >> 6, c = i & 63;
        tile[r][c] = W[(size_t)(k0 + r) * 1024 + n0 + c];
    }
    __syncthreads();
    for (int i = t; i < 4096; i += 256) {
        int rn = i >> 6, ck = i & 63;
        T[(size_t)(n0 + rn) * 1024 + k0 + ck] = f2bf(tile[ck][rn]);
    }
}

// ---------------------------------------------------------------------------
// MFMA GEMM core, 128(M)x64(N) tile, BK=32, ping-pong LDS, ONE barrier per
// K-iter (R8 config, measured 65 us / MfmaUtil 15.4% / 1.15 TB/s).
// 4 waves, each 64x32 (4x2 MFMA tiles).  LDS 24 KB, VGPR ~68 -> 6 blocks/CU.
// [R9 lesson: 128x128 ping-pong (32KB/136VGPR/3blk-CU) HALVES HBM efficiency
//  and raises FETCH 53->80 MB -- do not revisit without new evidence.]
// ---------------------------------------------------------------------------
__device__ __forceinline__
void gemm_core(const ushortT* __restrict__ A, const ushortT* __restrict__ Bt,
               int m0, int n0, ushortT* As, ushortT* Bs, f32x4 (&acc)[4][2])
{
    const int t = threadIdx.x;
    const int l = t & 63, w = t >> 6;
    const int wm = (w >> 1) * 64, wn = (w & 1) * 32;
    const int lm = l & 15, q = l >> 4;

    const int r0 = t >> 2, c0 = (t & 3) * 8;
    const ushortT* Ag0 = A  + (size_t)(m0 + r0) * 1024 + c0;       // rows 0..63
    const ushortT* Ag1 = Ag0 + (size_t)64 * 1024;                  // rows 64..127
    const ushortT* Bg0 = Bt + (size_t)(n0 + r0) * 1024 + c0;       // rows 0..63
    ushortT* La0 = As + t * 8;
    ushortT* La1 = As + 2048 + t * 8;
    ushortT* Lb0 = Bs + t * 8;

    gl2lds16(Ag0, La0);
    gl2lds16(Ag1, La1);
    gl2lds16(Bg0, Lb0);

    for (int kt = 0; kt < 1024 / BK; ++kt) {
        __syncthreads();   // buf[kt&1] loads complete; prev ds_reads complete
        if (kt + 1 < 1024 / BK) {      // prefetch k+1 into the other buffer
            int ko = (kt + 1) * BK;
            int bo = ((kt + 1) & 1) ? 4096 : 0;
            int bo2 = ((kt + 1) & 1) ? 2048 : 0;
            gl2lds16(Ag0 + ko, La0 + bo);
            gl2lds16(Ag1 + ko, La1 + bo);
            gl2lds16(Bg0 + ko, Lb0 + bo2);
        }
        const ushortT* Ab = As + ((kt & 1) ? 4096 : 0);
        const ushortT* Bb = Bs + ((kt & 1) ? 2048 : 0);
        short8 af[4], bf[2];
#pragma unroll
        for (int i = 0; i < 4; ++i)
            af[i] = *(const short8*)&Ab[(wm + i * 16 + lm) * 32 + q * 8];
#pragma unroll
        for (int j = 0; j < 2; ++j)
            bf[j] = *(const short8*)&Bb[(wn + j * 16 + lm) * 32 + q * 8];
#pragma unroll
        for (int i = 0; i < 4; ++i)
#pragma unroll
            for (int j = 0; j < 2; ++j)
                acc[i][j] = __builtin_amdgcn_mfma_f32_16x16x32_bf16(af[i], bf[j], acc[i][j], 0, 0, 0);
    }
}

// Fused Q/K/V + gate-logit: grid (16,24,4).
// z==0: SCALE folded into Q.  z==2: V stored transposed Vt[b,h,d,N].
// z==3: no store; gelu -> dot with Wg2 -> atomicAdd into glogit[m].
__global__ __launch_bounds__(256)
void gemm_qkvg(const ushortT* __restrict__ xb,
               const ushortT* Wt0, const ushortT* Wt1, const ushortT* Wt2, const ushortT* Wt3,
               const float* bz0, const float* bz1, const float* bz2, const float* bz3,
               const float* __restrict__ Wg2,
               ushortT* O0, ushortT* O1, ushortT* O2, float* __restrict__ glogit)
{
    __shared__ ushortT As[2 * 128 * 32];
    __shared__ ushortT Bs[2 * 64 * 32];
    const int z = blockIdx.z;
    const ushortT* Wt  = z == 0 ? Wt0 : z == 1 ? Wt1 : z == 2 ? Wt2 : Wt3;
    const float*  bias = z == 0 ? bz0 : z == 1 ? bz1 : z == 2 ? bz2 : bz3;
    const int m0 = blockIdx.y * 128, n0 = blockIdx.x * 64;

    f32x4 acc[4][2] = {};
    gemm_core(xb, Wt, m0, n0, As, Bs, acc);

    const int t = threadIdx.x, l = t & 63, w = t >> 6;
    const int wm = (w >> 1) * 64, wn = (w & 1) * 32;
    const int lm = l & 15, q = l >> 4;

    if (z == 3) {
        float part[4][4] = {};
#pragma unroll
        for (int i = 0; i < 4; ++i)
#pragma unroll
            for (int j = 0; j < 2; ++j) {
                int n = n0 + wn + j * 16 + lm;
                float bn = bias[n];
                float w2 = Wg2[n];
#pragma unroll
                for (int r = 0; r < 4; ++r) {
                    float v = acc[i][j][r] + bn;
                    v = 0.5f * v * (1.0f + erff(v * 0.70710678118654752f));
                    part[i][r] += v * w2;
                }
            }
#pragma unroll
        for (int i = 0; i < 4; ++i)
#pragma unroll
            for (int r = 0; r < 4; ++r) {
                float p = part[i][r];
#pragma unroll
                for (int msk = 1; msk < 16; msk <<= 1) p += __shfl_xor(p, msk, 16);
                if (lm == 0)
                    atomicAdd(&glogit[m0 + wm + i * 16 + q * 4 + r], p);
            }
        return;
    }

    ushortT* O = z == 0 ? O0 : z == 1 ? O1 : O2;
#pragma unroll
    for (int i = 0; i < 4; ++i)
#pragma unroll
        for (int j = 0; j < 2; ++j) {
            int n = n0 + wn + j * 16 + lm;
            float bn = bias[n];
#pragma unroll
            for (int r = 0; r < 4; ++r) {
                int m = m0 + wm + i * 16 + q * 4 + r;
                float v = acc[i][j][r] + bn;
                if (z == 0) v *= SCALE;
                if (z == 2) {  // Vt[((b*16+h)*64+dd)*1536 + nn]
                    int b = m / Nseq, nn = m - b * Nseq;
                    int h = n >> 6, dd = n & 63;
                    O[(size_t)((b * 16 + h) * 64 + dd) * Nseq + nn] = f2bf(v);
                } else {
                    O[(size_t)m * 1024 + n] = f2bf(v);
                }
            }
        }
}

// Output projection: AO bf16 @ WoT -> f32 out.  grid (16,24), 128x64 tiles.
__global__ __launch_bounds__(256)
void gemm_out(const ushortT* __restrict__ AO, const ushortT* __restrict__ WtO,
              const float* __restrict__ bias, float* __restrict__ C)
{
    __shared__ ushortT As[2 * 128 * 32];
    __shared__ ushortT Bs[2 * 64 * 32];
    const int m0 = blockIdx.y * 128, n0 = blockIdx.x * 64;

    f32x4 acc[4][2] = {};
    gemm_core(AO, WtO, m0, n0, As, Bs, acc);

    const int t = threadIdx.x, l = t & 63, w = t >> 6;
    const int wm = (w >> 1) * 64, wn = (w & 1) * 32;
    const int lm = l & 15, q = l >> 4;
#pragma unroll
    for (int i = 0; i < 4; ++i)
#pragma unroll
        for (int j = 0; j < 2; ++j) {
            int n = n0 + wn + j * 16 + lm;
            float bn = bias[n];
#pragma unroll
            for (int r = 0; r < 4; ++r) {
                int m = m0 + wm + i * 16 + q * 4 + r;
                C[(size_t)m * 1024 + n] = acc[i][j][r] + bn;
            }
        }
}

// ---------------------------------------------------------------------------
// MFMA flash attention: 2 waves/block split the KEY dimension (parity-
// interleaved 64-key tiles; diagonal owned by parity-matching wave).  With
// m==0 (no max tracking) partial (l,t,O) over disjoint key sets sum exactly;
// merged once through LDS in the epilogue.  32 q-rows per block.
// ---------------------------------------------------------------------------
__global__ __launch_bounds__(128)
void attn_mfma(const ushortT* __restrict__ Q, const ushortT* __restrict__ K,
               const ushortT* __restrict__ Vt, const float* __restrict__ glogit,
               const float* __restrict__ bg2, ushortT* __restrict__ AO,
               float* __restrict__ ent)
{
    __shared__ ushortT Ps[2][32][72];
    __shared__ float mbuf[3072];        // 2048 oacc + 512 l + 512 t

    const int t  = threadIdx.x;
    const int w  = t >> 6, l = t & 63;
    const int ln = l & 15, q4 = l >> 4;
    const int bh = blockIdx.x, b = bh >> 4, h = bh & 15;
    const int q32 = (int)gridDim.y - 1 - (int)blockIdx.y;   // big-first
    const int wq = q32 * 32;
    const int kd = wq >> 6;                       // diagonal 64-key tile
    const int sbmax = ((wq >> 4) & 3) + 1;

    const ushortT* Qp = Q + (size_t)(b * Nseq + wq + ln) * Dmod + h * DHd + q4 * 8;
    short8 qf[2][2];
    qf[0][0] = *(const short8*)(Qp);
    qf[0][1] = *(const short8*)(Qp + 32);
    qf[1][0] = *(const short8*)(Qp + (size_t)16 * Dmod);
    qf[1][1] = *(const short8*)(Qp + (size_t)16 * Dmod + 32);

    float l_lane[2][4] = {}, t_lane[2][4] = {};
    f32x4 oacc[2][4] = {};

    const ushortT* Kbase = K  + (size_t)(b * Nseq) * Dmod + h * DHd + q4 * 8;
    const ushortT* Vbase = Vt + ((size_t)(b * 16 + h) * 64) * Nseq + q4 * 8;

    short8 kc[4][2];
    {
        const ushortT* Kp = Kbase + (size_t)(w * 64 + ln) * Dmod;
#pragma unroll
        for (int nb = 0; nb < 4; ++nb) {
            kc[nb][0] = *(const short8*)(Kp + (size_t)nb * 16 * Dmod);
            kc[nb][1] = *(const short8*)(Kp + (size_t)nb * 16 * Dmod + 32);
        }
    }

    for (int kt = w; kt < kd; kt += 2) {
        const int k0 = kt * 64;
        const ushortT* Vp = Vbase + (size_t)ln * Nseq + k0;
        short8 vf[4][2];
#pragma unroll
        for (int nb = 0; nb < 4; ++nb) {
            vf[nb][0] = *(const short8*)(Vp + (size_t)nb * 16 * Nseq);
            vf[nb][1] = *(const short8*)(Vp + (size_t)nb * 16 * Nseq + 32);
        }
        short8 kn[4][2];
        {
            int prow = k0 + 128; if (prow > Nseq - 64) prow = Nseq - 64;
            const ushortT* Kp = Kbase + (size_t)(prow + ln) * Dmod;
#pragma unroll
            for (int nb = 0; nb < 4; ++nb) {
                kn[nb][0] = *(const short8*)(Kp + (size_t)nb * 16 * Dmod);
                kn[nb][1] = *(const short8*)(Kp + (size_t)nb * 16 * Dmod + 32);
            }
        }
        f32x4 sacc[2][4];
#pragma unroll
        for (int g = 0; g < 2; ++g)
#pragma unroll
            for (int nb = 0; nb < 4; ++nb) {
                f32x4 a = {};
                a = __builtin_amdgcn_mfma_f32_16x16x32_bf16(qf[g][0], kc[nb][0], a, 0, 0, 0);
                a = __builtin_amdgcn_mfma_f32_16x16x32_bf16(qf[g][1], kc[nb][1], a, 0, 0, 0);
                sacc[g][nb] = a;
            }
#pragma unroll
        for (int g = 0; g < 2; ++g)
#pragma unroll
            for (int nb = 0; nb < 4; ++nb)
#pragma unroll
                for (int r = 0; r < 4; ++r) {
                    float sv = sacc[g][nb][r];
                    float ev = __expf(sv);
                    l_lane[g][r] += ev;
                    t_lane[g][r] += ev * sv;
                    Ps[w][g * 16 + q4 * 4 + r][nb * 16 + ln] = f2bf(ev);
                }
        short8 pf[2][2];
#pragma unroll
        for (int g = 0; g < 2; ++g) {
            pf[g][0] = *(const short8*)&Ps[w][g * 16 + ln][q4 * 8];
            pf[g][1] = *(const short8*)&Ps[w][g * 16 + ln][32 + q4 * 8];
        }
#pragma unroll
        for (int g = 0; g < 2; ++g)
#pragma unroll
            for (int nb = 0; nb < 4; ++nb) {
                oacc[g][nb] = __builtin_amdgcn_mfma_f32_16x16x32_bf16(pf[g][0], vf[nb][0], oacc[g][nb], 0, 0, 0);
                oacc[g][nb] = __builtin_amdgcn_mfma_f32_16x16x32_bf16(pf[g][1], vf[nb][1], oacc[g][nb], 0, 0, 0);
            }
#pragma unroll
        for (int nb = 0; nb < 4; ++nb) { kc[nb][0] = kn[nb][0]; kc[nb][1] = kn[nb][1]; }
    }

    // ---- diagonal tile: owned by the wave whose parity matches kd ----
    if ((kd & 1) == w) {
        const int k0 = kd * 64;
        const ushortT* Vp = Vbase + (size_t)ln * Nseq + k0;
        short8 vf[4][2];
#pragma unroll
        for (int nb = 0; nb < 4; ++nb) {
            vf[nb][0] = *(const short8*)(Vp + (size_t)nb * 16 * Nseq);
            vf[nb][1] = *(const short8*)(Vp + (size_t)nb * 16 * Nseq + 32);
        }
        f32x4 sacc[2][4];
#pragma unroll
        for (int g = 0; g < 2; ++g)
#pragma unroll
            for (int nb = 0; nb < 4; ++nb)
                if (nb <= sbmax) {
                    f32x4 a = {};
                    a = __builtin_amdgcn_mfma_f32_16x16x32_bf16(qf[g][0], kc[nb][0], a, 0, 0, 0);
                    a = __builtin_amdgcn_mfma_f32_16x16x32_bf16(qf[g][1], kc[nb][1], a, 0, 0, 0);
                    sacc[g][nb] = a;
                }
#pragma unroll
        for (int g = 0; g < 2; ++g)
#pragma unroll
            for (int nb = 0; nb < 4; ++nb)
#pragma unroll
                for (int r = 0; r < 4; ++r) {
                    float ev = 0.f;
                    if (nb <= sbmax) {
                        int kg = k0 + nb * 16 + ln;
                        int qg = wq + g * 16 + q4 * 4 + r;
                        float sv = sacc[g][nb][r];
                        ev = (kg <= qg) ? __expf(sv) : 0.f;
                        l_lane[g][r] += ev;
                        t_lane[g][r] += ev * sv;
                    }
                    Ps[w][g * 16 + q4 * 4 + r][nb * 16 + ln] = f2bf(ev);
                }
        short8 pf[2][2];
#pragma unroll
        for (int g = 0; g < 2; ++g) {
            pf[g][0] = *(const short8*)&Ps[w][g * 16 + ln][q4 * 8];
            pf[g][1] = *(const short8*)&Ps[w][g * 16 + ln][32 + q4 * 8];
        }
#pragma unroll
        for (int g = 0; g < 2; ++g)
#pragma unroll
            for (int nb = 0; nb < 4; ++nb) {
                oacc[g][nb] = __builtin_amdgcn_mfma_f32_16x16x32_bf16(pf[g][0], vf[nb][0], oacc[g][nb], 0, 0, 0);
                oacc[g][nb] = __builtin_amdgcn_mfma_f32_16x16x32_bf16(pf[g][1], vf[nb][1], oacc[g][nb], 0, 0, 0);
            }
    }

    // ---- merge wave1 partials into wave0 (exact: disjoint key sets, m==0) ----
    if (w == 1) {
#pragma unroll
        for (int g = 0; g < 2; ++g)
#pragma unroll
            for (int nb = 0; nb < 4; ++nb)
#pragma unroll
                for (int r = 0; r < 4; ++r)
                    mbuf[(((g << 2) | nb) * 4 + r) * 64 + l] = oacc[g][nb][r];
#pragma unroll
        for (int g = 0; g < 2; ++g)
#pragma unroll
            for (int r = 0; r < 4; ++r) {
                mbuf[2048 + ((g << 2) | r) * 64 + l] = l_lane[g][r];
                mbuf[2560 + ((g << 2) | r) * 64 + l] = t_lane[g][r];
            }
    }
    __syncthreads();
    if (w == 1) return;
#pragma unroll
    for (int g = 0; g < 2; ++g) {
#pragma unroll
        for (int nb = 0; nb < 4; ++nb)
#pragma unroll
            for (int r = 0; r < 4; ++r)
                oacc[g][nb][r] += mbuf[(((g << 2) | nb) * 4 + r) * 64 + l];
#pragma unroll
        for (int r = 0; r < 4; ++r) {
            l_lane[g][r] += mbuf[2048 + ((g << 2) | r) * 64 + l];
            t_lane[g][r] += mbuf[2560 + ((g << 2) | r) * 64 + l];
        }
    }

    // ---- epilogue (wave 0 only) ----
    const float bg2v = bg2[0];
#pragma unroll
    for (int g = 0; g < 2; ++g) {
        float sc[4];
#pragma unroll
        for (int r = 0; r < 4; ++r) {
            float lv = l_lane[g][r], tv = t_lane[g][r];
#pragma unroll
            for (int msk = 1; msk < 16; msk <<= 1) {
                lv += __shfl_xor(lv, msk, 16);
                tv += __shfl_xor(tv, msk, 16);
            }
            int qg = wq + g * 16 + q4 * 4 + r;
            float inv = 1.f / lv;
            if (ln == 0)
                ent[((size_t)b * NH + h) * Nseq + qg] = logf(lv) - tv * inv;
            float logit = glogit[b * Nseq + qg] + bg2v;
            sc[r] = inv / (1.f + __expf(-logit));
        }
#pragma unroll
        for (int nb = 0; nb < 4; ++nb)
#pragma unroll
            for (int r = 0; r < 4; ++r) {
                int qg = wq + g * 16 + q4 * 4 + r;
                AO[(size_t)(b * Nseq + qg) * Dmod + h * DHd + nb * 16 + ln] =
                    f2bf(oacc[g][nb][r] * sc[r]);
            }
    }
}

// ---------------------------------------------------------------------------
extern "C" void kernel_launch(void* const* d_in, const int* in_sizes, int n_in,
                              void* d_out, int out_size, void* d_ws, size_t ws_size,
                              hipStream_t stream)
{
    const float* x   = (const float*)d_in[0];
    const float* Wq  = (const float*)d_in[2];
    const float* bq  = (const float*)d_in[3];
    const float* Wk  = (const float*)d_in[4];
    const float* bk  = (const float*)d_in[5];
    const float* Wv  = (const float*)d_in[6];
    const float* bv  = (const float*)d_in[7];
    const float* Wg1 = (const float*)d_in[8];
    const float* bg1 = (const float*)d_in[9];
    const float* Wg2 = (const float*)d_in[10];
    const float* bg2 = (const float*)d_in[11];
    const float* Wo  = (const float*)d_in[12];
    const float* bo  = (const float*)d_in[13];

    const size_t NE = (size_t)MTOT * Dmod;
    ushortT* p   = (ushortT*)d_ws;
    ushortT* Qw  = p; p += NE;
    ushortT* Kw  = p; p += NE;
    ushortT* Vtw = p; p += NE;       // V transposed: [B,H,64,Nseq]
    ushortT* AO  = p; p += NE;
    ushortT* xb  = p; p += NE;
    ushortT* WtQ = p; p += (size_t)1024 * 1024;
    ushortT* WtK = p; p += (size_t)1024 * 1024;
    ushortT* WtV = p; p += (size_t)1024 * 1024;
    ushortT* WtG = p; p += (size_t)1024 * 1024;
    ushortT* WtO = p; p += (size_t)1024 * 1024;
    float* glogit = (float*)p;       // MTOT floats

    float* out_f = (float*)d_out;
    float* ent_f = out_f + NE;

    prep_kernel<<<dim3(16, 16, 6), 256, 0, stream>>>(Wq, Wk, Wv, Wg1, Wo,
                                                     WtQ, WtK, WtV, WtG, WtO,
                                                     x, xb, glogit);
    gemm_qkvg<<<dim3(16, 24, 4), 256, 0, stream>>>(xb, WtQ, WtK, WtV, WtG,
                                                   bq, bk, bv, bg1, Wg2,
                                                   Qw, Kw, Vtw, glogit);
    attn_mfma<<<dim3(Bsz * NH, Nseq / 32), 128, 0, stream>>>(Qw, Kw, Vtw, glogit,
                                                             bg2, AO, ent_f);
    gemm_out<<<dim3(16, 24), 256, 0, stream>>>(AO, WtO, bo, out_f);
}

// Round 11
// 227.362 us; speedup vs baseline: 1.1772x; 1.0119x over previous
//
#include <hip/hip_runtime.h>
#include <hip/hip_bf16.h>
#include <math.h>

#define Bsz  2
#define Nseq 1536
#define Dmod 1024
#define NH   16
#define DHd  64
#define MTOT (Bsz*Nseq)          // 3072
#define SCALE 0.125f             // DH^-0.5
#define BK   32

typedef short  short8 __attribute__((ext_vector_type(8)));
typedef float  f32x4  __attribute__((ext_vector_type(4)));
typedef unsigned short u16x4 __attribute__((ext_vector_type(4)));
typedef unsigned short ushortT;

__device__ __forceinline__ float b2f(__hip_bfloat16 v) { return __bfloat162float(v); }
__device__ __forceinline__ unsigned short f2bf(float f) {   // RNE f32->bf16
    union { float f; unsigned u; } a; a.f = f;
    unsigned r = a.u + 0x7fffu + ((a.u >> 16) & 1u);
    return (unsigned short)(r >> 16);
}

// async global->LDS, 16B per lane (wave-uniform base + lane*16)
__device__ __forceinline__ void gl2lds16(const ushortT* g, ushortT* lds) {
    __builtin_amdgcn_global_load_lds(
        (const __attribute__((address_space(1))) unsigned int*)(g),
        (__attribute__((address_space(3))) unsigned int*)(lds),
        16, 0, 0);
}

// ---------------------------------------------------------------------------
// prep: z<5 -> W f32 [k][n] -> Wt bf16 [n][k] transpose (float4 reads,
// u16x4 stores);  z==5 -> x f32->bf16 (grid-stride) + zero gate_logit.
// ---------------------------------------------------------------------------
__global__ __launch_bounds__(256)
void prep_kernel(const float* W0, const float* W1, const float* W2,
                 const float* W3, const float* W4,
                 ushortT* T0, ushortT* T1, ushortT* T2, ushortT* T3, ushortT* T4,
                 const float* __restrict__ x, ushortT* __restrict__ xb,
                 float* __restrict__ glogit)
{
    const int z = blockIdx.z;
    const int t = threadIdx.x;
    if (z == 5) {
        const int bi = blockIdx.y * 16 + blockIdx.x;   // 0..255
        const size_t NEl = (size_t)MTOT * Dmod;
        for (size_t i = ((size_t)bi * 256 + t) * 4; i < NEl; i += (size_t)256 * 256 * 4) {
            float4 v = *(const float4*)(x + i);
            u16x4 o = { f2bf(v.x), f2bf(v.y), f2bf(v.z), f2bf(v.w) };
            *(u16x4*)(xb + i) = o;
        }
        if (t < 12) glogit[bi * 12 + t] = 0.f;
        return;
    }
    __shared__ float tile[64][65];
    const float* W = z == 0 ? W0 : z == 1 ? W1 : z == 2 ? W2 : z == 3 ? W3 : W4;
    ushortT*     T = z == 0 ? T0 : z == 1 ? T1 : z == 2 ? T2 : z == 3 ? T3 : T4;
    const int k0 = blockIdx.x * 64, n0 = blockIdx.y * 64;
    for (int i = t; i < 1024; i += 256) {            // 64 rows x 16 col-groups
        int r = i >> 4, c4 = (i & 15) * 4;
        float4 v = *(const float4*)&W[(size_t)(k0 + r) * 1024 + n0 + c4];
        tile[r][c4 + 0] = v.x; tile[r][c4 + 1] = v.y;
        tile[r][c4 + 2] = v.z; tile[r][c4 + 3] = v.w;
    }
    __syncthreads();
    for (int i = t; i < 1024; i += 256) {            // 64 n-rows x 16 k-groups
        int rn = i >> 4, ck4 = (i & 15) * 4;
        u16x4 o = { f2bf(tile[ck4 + 0][rn]), f2bf(tile[ck4 + 1][rn]),
                    f2bf(tile[ck4 + 2][rn]), f2bf(tile[ck4 + 3][rn]) };
        *(u16x4*)&T[(size_t)(n0 + rn) * 1024 + k0 + ck4] = o;
    }
}

// ---------------------------------------------------------------------------
// MFMA GEMM core, 128(M)x64(N) tile, BK=32, ping-pong LDS, ONE barrier per
// K-iter (R8 config, measured 66 us / MfmaUtil 15.8% / 1.14 TB/s).
// [R9 lesson: 128x128 ping-pong (32KB/136VGPR/3blk-CU) HALVES HBM efficiency
//  and raises FETCH 53->80 MB -- do not revisit without new evidence.]
// ---------------------------------------------------------------------------
__device__ __forceinline__
void gemm_core(const ushortT* __restrict__ A, const ushortT* __restrict__ Bt,
               int m0, int n0, ushortT* As, ushortT* Bs, f32x4 (&acc)[4][2])
{
    const int t = threadIdx.x;
    const int l = t & 63, w = t >> 6;
    const int wm = (w >> 1) * 64, wn = (w & 1) * 32;
    const int lm = l & 15, q = l >> 4;

    const int r0 = t >> 2, c0 = (t & 3) * 8;
    const ushortT* Ag0 = A  + (size_t)(m0 + r0) * 1024 + c0;
    const ushortT* Ag1 = Ag0 + (size_t)64 * 1024;
    const ushortT* Bg0 = Bt + (size_t)(n0 + r0) * 1024 + c0;
    ushortT* La0 = As + t * 8;
    ushortT* La1 = As + 2048 + t * 8;
    ushortT* Lb0 = Bs + t * 8;

    gl2lds16(Ag0, La0);
    gl2lds16(Ag1, La1);
    gl2lds16(Bg0, Lb0);

    for (int kt = 0; kt < 1024 / BK; ++kt) {
        __syncthreads();
        if (kt + 1 < 1024 / BK) {
            int ko = (kt + 1) * BK;
            int bo = ((kt + 1) & 1) ? 4096 : 0;
            int bo2 = ((kt + 1) & 1) ? 2048 : 0;
            gl2lds16(Ag0 + ko, La0 + bo);
            gl2lds16(Ag1 + ko, La1 + bo);
            gl2lds16(Bg0 + ko, Lb0 + bo2);
        }
        const ushortT* Ab = As + ((kt & 1) ? 4096 : 0);
        const ushortT* Bb = Bs + ((kt & 1) ? 2048 : 0);
        short8 af[4], bf[2];
#pragma unroll
        for (int i = 0; i < 4; ++i)
            af[i] = *(const short8*)&Ab[(wm + i * 16 + lm) * 32 + q * 8];
#pragma unroll
        for (int j = 0; j < 2; ++j)
            bf[j] = *(const short8*)&Bb[(wn + j * 16 + lm) * 32 + q * 8];
#pragma unroll
        for (int i = 0; i < 4; ++i)
#pragma unroll
            for (int j = 0; j < 2; ++j)
                acc[i][j] = __builtin_amdgcn_mfma_f32_16x16x32_bf16(af[i], bf[j], acc[i][j], 0, 0, 0);
    }
}

// 64x64 core: 4 waves each 32x32 (2x2 frags), ping-pong, one barrier/iter.
// For gemm_out: grid 768 blocks = 3/CU (vs 384 = 1.5/CU at 128x64).
__device__ __forceinline__
void gemm_core_sq(const ushortT* __restrict__ A, const ushortT* __restrict__ Bt,
                  int m0, int n0, ushortT* As, ushortT* Bs, f32x4 (&acc)[2][2])
{
    const int t = threadIdx.x;
    const int l = t & 63, w = t >> 6;
    const int wm = (w >> 1) * 32, wn = (w & 1) * 32;
    const int lm = l & 15, q = l >> 4;

    const int r0 = t >> 2, c0 = (t & 3) * 8;
    const ushortT* Ag = A  + (size_t)(m0 + r0) * 1024 + c0;
    const ushortT* Bg = Bt + (size_t)(n0 + r0) * 1024 + c0;
    ushortT* La = As + t * 8;
    ushortT* Lb = Bs + t * 8;

    gl2lds16(Ag, La);
    gl2lds16(Bg, Lb);

    for (int kt = 0; kt < 1024 / BK; ++kt) {
        __syncthreads();
        if (kt + 1 < 1024 / BK) {
            int ko = (kt + 1) * BK;
            int bo = ((kt + 1) & 1) ? 2048 : 0;
            gl2lds16(Ag + ko, La + bo);
            gl2lds16(Bg + ko, Lb + bo);
        }
        const ushortT* Ab = As + ((kt & 1) ? 2048 : 0);
        const ushortT* Bb = Bs + ((kt & 1) ? 2048 : 0);
        short8 af[2], bf[2];
#pragma unroll
        for (int i = 0; i < 2; ++i) {
            af[i] = *(const short8*)&Ab[(wm + i * 16 + lm) * 32 + q * 8];
            bf[i] = *(const short8*)&Bb[(wn + i * 16 + lm) * 32 + q * 8];
        }
#pragma unroll
        for (int i = 0; i < 2; ++i)
#pragma unroll
            for (int j = 0; j < 2; ++j)
                acc[i][j] = __builtin_amdgcn_mfma_f32_16x16x32_bf16(af[i], bf[j], acc[i][j], 0, 0, 0);
    }
}

// Fused Q/K/V + gate-logit: grid (16,24,4).
// z==0: SCALE folded into Q.  z==2: V stored transposed Vt[b,h,d,N].
// z==3: no store; gelu -> dot with Wg2 -> atomicAdd into glogit[m].
__global__ __launch_bounds__(256)
void gemm_qkvg(const ushortT* __restrict__ xb,
               const ushortT* Wt0, const ushortT* Wt1, const ushortT* Wt2, const ushortT* Wt3,
               const float* bz0, const float* bz1, const float* bz2, const float* bz3,
               const float* __restrict__ Wg2,
               ushortT* O0, ushortT* O1, ushortT* O2, float* __restrict__ glogit)
{
    __shared__ ushortT As[2 * 128 * 32];
    __shared__ ushortT Bs[2 * 64 * 32];
    const int z = blockIdx.z;
    const ushortT* Wt  = z == 0 ? Wt0 : z == 1 ? Wt1 : z == 2 ? Wt2 : Wt3;
    const float*  bias = z == 0 ? bz0 : z == 1 ? bz1 : z == 2 ? bz2 : bz3;
    const int m0 = blockIdx.y * 128, n0 = blockIdx.x * 64;

    f32x4 acc[4][2] = {};
    gemm_core(xb, Wt, m0, n0, As, Bs, acc);

    const int t = threadIdx.x, l = t & 63, w = t >> 6;
    const int wm = (w >> 1) * 64, wn = (w & 1) * 32;
    const int lm = l & 15, q = l >> 4;

    if (z == 3) {
        float part[4][4] = {};
#pragma unroll
        for (int i = 0; i < 4; ++i)
#pragma unroll
            for (int j = 0; j < 2; ++j) {
                int n = n0 + wn + j * 16 + lm;
                float bn = bias[n];
                float w2 = Wg2[n];
#pragma unroll
                for (int r = 0; r < 4; ++r) {
                    float v = acc[i][j][r] + bn;
                    v = 0.5f * v * (1.0f + erff(v * 0.70710678118654752f));
                    part[i][r] += v * w2;
                }
            }
#pragma unroll
        for (int i = 0; i < 4; ++i)
#pragma unroll
            for (int r = 0; r < 4; ++r) {
                float p = part[i][r];
#pragma unroll
                for (int msk = 1; msk < 16; msk <<= 1) p += __shfl_xor(p, msk, 16);
                if (lm == 0)
                    atomicAdd(&glogit[m0 + wm + i * 16 + q * 4 + r], p);
            }
        return;
    }

    ushortT* O = z == 0 ? O0 : z == 1 ? O1 : O2;
#pragma unroll
    for (int i = 0; i < 4; ++i)
#pragma unroll
        for (int j = 0; j < 2; ++j) {
            int n = n0 + wn + j * 16 + lm;
            float bn = bias[n];
#pragma unroll
            for (int r = 0; r < 4; ++r) {
                int m = m0 + wm + i * 16 + q * 4 + r;
                float v = acc[i][j][r] + bn;
                if (z == 0) v *= SCALE;
                if (z == 2) {  // Vt[((b*16+h)*64+dd)*1536 + nn]
                    int b = m / Nseq, nn = m - b * Nseq;
                    int h = n >> 6, dd = n & 63;
                    O[(size_t)((b * 16 + h) * 64 + dd) * Nseq + nn] = f2bf(v);
                } else {
                    O[(size_t)m * 1024 + n] = f2bf(v);
                }
            }
        }
}

// Output projection: AO bf16 @ WoT -> f32 out.  grid (16,48), 64x64 tiles.
__global__ __launch_bounds__(256)
void gemm_out(const ushortT* __restrict__ AO, const ushortT* __restrict__ WtO,
              const float* __restrict__ bias, float* __restrict__ C)
{
    __shared__ ushortT As[2 * 64 * 32];
    __shared__ ushortT Bs[2 * 64 * 32];
    const int m0 = blockIdx.y * 64, n0 = blockIdx.x * 64;

    f32x4 acc[2][2] = {};
    gemm_core_sq(AO, WtO, m0, n0, As, Bs, acc);

    const int t = threadIdx.x, l = t & 63, w = t >> 6;
    const int wm = (w >> 1) * 32, wn = (w & 1) * 32;
    const int lm = l & 15, q = l >> 4;
#pragma unroll
    for (int i = 0; i < 2; ++i)
#pragma unroll
        for (int j = 0; j < 2; ++j) {
            int n = n0 + wn + j * 16 + lm;
            float bn = bias[n];
#pragma unroll
            for (int r = 0; r < 4; ++r) {
                int m = m0 + wm + i * 16 + q * 4 + r;
                C[(size_t)m * 1024 + n] = acc[i][j][r] + bn;
            }
        }
}

// ---------------------------------------------------------------------------
// MFMA flash attention: 2 waves/block split the KEY dimension (parity-
// interleaved 64-key tiles; diagonal owned by parity-matching wave).  With
// m==0 (no max tracking) partial (l,t,O) over disjoint key sets sum exactly;
// merged once through LDS in the epilogue.  32 q-rows per block.
// ---------------------------------------------------------------------------
__global__ __launch_bounds__(128)
void attn_mfma(const ushortT* __restrict__ Q, const ushortT* __restrict__ K,
               const ushortT* __restrict__ Vt, const float* __restrict__ glogit,
               const float* __restrict__ bg2, ushortT* __restrict__ AO,
               float* __restrict__ ent)
{
    __shared__ ushortT Ps[2][32][72];
    __shared__ float mbuf[3072];        // 2048 oacc + 512 l + 512 t

    const int t  = threadIdx.x;
    const int w  = t >> 6, l = t & 63;
    const int ln = l & 15, q4 = l >> 4;
    const int bh = blockIdx.x, b = bh >> 4, h = bh & 15;
    const int q32 = (int)gridDim.y - 1 - (int)blockIdx.y;   // big-first
    const int wq = q32 * 32;
    const int kd = wq >> 6;                       // diagonal 64-key tile
    const int sbmax = ((wq >> 4) & 3) + 1;

    const ushortT* Qp = Q + (size_t)(b * Nseq + wq + ln) * Dmod + h * DHd + q4 * 8;
    short8 qf[2][2];
    qf[0][0] = *(const short8*)(Qp);
    qf[0][1] = *(const short8*)(Qp + 32);
    qf[1][0] = *(const short8*)(Qp + (size_t)16 * Dmod);
    qf[1][1] = *(const short8*)(Qp + (size_t)16 * Dmod + 32);

    float l_lane[2][4] = {}, t_lane[2][4] = {};
    f32x4 oacc[2][4] = {};

    const ushortT* Kbase = K  + (size_t)(b * Nseq) * Dmod + h * DHd + q4 * 8;
    const ushortT* Vbase = Vt + ((size_t)(b * 16 + h) * 64) * Nseq + q4 * 8;

    short8 kc[4][2];
    {
        const ushortT* Kp = Kbase + (size_t)(w * 64 + ln) * Dmod;
#pragma unroll
        for (int nb = 0; nb < 4; ++nb) {
            kc[nb][0] = *(const short8*)(Kp + (size_t)nb * 16 * Dmod);
            kc[nb][1] = *(const short8*)(Kp + (size_t)nb * 16 * Dmod + 32);
        }
    }

    for (int kt = w; kt < kd; kt += 2) {
        const int k0 = kt * 64;
        const ushortT* Vp = Vbase + (size_t)ln * Nseq + k0;
        short8 vf[4][2];
#pragma unroll
        for (int nb = 0; nb < 4; ++nb) {
            vf[nb][0] = *(const short8*)(Vp + (size_t)nb * 16 * Nseq);
            vf[nb][1] = *(const short8*)(Vp + (size_t)nb * 16 * Nseq + 32);
        }
        short8 kn[4][2];
        {
            int prow = k0 + 128; if (prow > Nseq - 64) prow = Nseq - 64;
            const ushortT* Kp = Kbase + (size_t)(prow + ln) * Dmod;
#pragma unroll
            for (int nb = 0; nb < 4; ++nb) {
                kn[nb][0] = *(const short8*)(Kp + (size_t)nb * 16 * Dmod);
                kn[nb][1] = *(const short8*)(Kp + (size_t)nb * 16 * Dmod + 32);
            }
        }
        f32x4 sacc[2][4];
#pragma unroll
        for (int g = 0; g < 2; ++g)
#pragma unroll
            for (int nb = 0; nb < 4; ++nb) {
                f32x4 a = {};
                a = __builtin_amdgcn_mfma_f32_16x16x32_bf16(qf[g][0], kc[nb][0], a, 0, 0, 0);
                a = __builtin_amdgcn_mfma_f32_16x16x32_bf16(qf[g][1], kc[nb][1], a, 0, 0, 0);
                sacc[g][nb] = a;
            }
#pragma unroll
        for (int g = 0; g < 2; ++g)
#pragma unroll
            for (int nb = 0; nb < 4; ++nb)
#pragma unroll
                for (int r = 0; r < 4; ++r) {
                    float sv = sacc[g][nb][r];
                    float ev = __expf(sv);
                    l_lane[g][r] += ev;
                    t_lane[g][r] += ev * sv;
                    Ps[w][g * 16 + q4 * 4 + r][nb * 16 + ln] = f2bf(ev);
                }
        short8 pf[2][2];
#pragma unroll
        for (int g = 0; g < 2; ++g) {
            pf[g][0] = *(const short8*)&Ps[w][g * 16 + ln][q4 * 8];
            pf[g][1] = *(const short8*)&Ps[w][g * 16 + ln][32 + q4 * 8];
        }
#pragma unroll
        for (int g = 0; g < 2; ++g)
#pragma unroll
            for (int nb = 0; nb < 4; ++nb) {
                oacc[g][nb] = __builtin_amdgcn_mfma_f32_16x16x32_bf16(pf[g][0], vf[nb][0], oacc[g][nb], 0, 0, 0);
                oacc[g][nb] = __builtin_amdgcn_mfma_f32_16x16x32_bf16(pf[g][1], vf[nb][1], oacc[g][nb], 0, 0, 0);
            }
#pragma unroll
        for (int nb = 0; nb < 4; ++nb) { kc[nb][0] = kn[nb][0]; kc[nb][1] = kn[nb][1]; }
    }

    // ---- diagonal tile: owned by the wave whose parity matches kd ----
    if ((kd & 1) == w) {
        const int k0 = kd * 64;
        const ushortT* Vp = Vbase + (size_t)ln * Nseq + k0;
        short8 vf[4][2];
#pragma unroll
        for (int nb = 0; nb < 4; ++nb) {
            vf[nb][0] = *(const short8*)(Vp + (size_t)nb * 16 * Nseq);
            vf[nb][1] = *(const short8*)(Vp + (size_t)nb * 16 * Nseq + 32);
        }
        f32x4 sacc[2][4];
#pragma unroll
        for (int g = 0; g < 2; ++g)
#pragma unroll
            for (int nb = 0; nb < 4; ++nb)
                if (nb <= sbmax) {
                    f32x4 a = {};
                    a = __builtin_amdgcn_mfma_f32_16x16x32_bf16(qf[g][0], kc[nb][0], a, 0, 0, 0);
                    a = __builtin_amdgcn_mfma_f32_16x16x32_bf16(qf[g][1], kc[nb][1], a, 0, 0, 0);
                    sacc[g][nb] = a;
                }
#pragma unroll
        for (int g = 0; g < 2; ++g)
#pragma unroll
            for (int nb = 0; nb < 4; ++nb)
#pragma unroll
                for (int r = 0; r < 4; ++r) {
                    float ev = 0.f;
                    if (nb <= sbmax) {
                        int kg = k0 + nb * 16 + ln;
                        int qg = wq + g * 16 + q4 * 4 + r;
                        float sv = sacc[g][nb][r];
                        ev = (kg <= qg) ? __expf(sv) : 0.f;
                        l_lane[g][r] += ev;
                        t_lane[g][r] += ev * sv;
                    }
                    Ps[w][g * 16 + q4 * 4 + r][nb * 16 + ln] = f2bf(ev);
                }
        short8 pf[2][2];
#pragma unroll
        for (int g = 0; g < 2; ++g) {
            pf[g][0] = *(const short8*)&Ps[w][g * 16 + ln][q4 * 8];
            pf[g][1] = *(const short8*)&Ps[w][g * 16 + ln][32 + q4 * 8];
        }
#pragma unroll
        for (int g = 0; g < 2; ++g)
#pragma unroll
            for (int nb = 0; nb < 4; ++nb) {
                oacc[g][nb] = __builtin_amdgcn_mfma_f32_16x16x32_bf16(pf[g][0], vf[nb][0], oacc[g][nb], 0, 0, 0);
                oacc[g][nb] = __builtin_amdgcn_mfma_f32_16x16x32_bf16(pf[g][1], vf[nb][1], oacc[g][nb], 0, 0, 0);
            }
    }

    // ---- merge wave1 partials into wave0 (exact: disjoint key sets, m==0) ----
    if (w == 1) {
#pragma unroll
        for (int g = 0; g < 2; ++g)
#pragma unroll
            for (int nb = 0; nb < 4; ++nb)
#pragma unroll
                for (int r = 0; r < 4; ++r)
                    mbuf[(((g << 2) | nb) * 4 + r) * 64 + l] = oacc[g][nb][r];
#pragma unroll
        for (int g = 0; g < 2; ++g)
#pragma unroll
            for (int r = 0; r < 4; ++r) {
                mbuf[2048 + ((g << 2) | r) * 64 + l] = l_lane[g][r];
                mbuf[2560 + ((g << 2) | r) * 64 + l] = t_lane[g][r];
            }
    }
    __syncthreads();
    if (w == 1) return;
#pragma unroll
    for (int g = 0; g < 2; ++g) {
#pragma unroll
        for (int nb = 0; nb < 4; ++nb)
#pragma unroll
            for (int r = 0; r < 4; ++r)
                oacc[g][nb][r] += mbuf[(((g << 2) | nb) * 4 + r) * 64 + l];
#pragma unroll
        for (int r = 0; r < 4; ++r) {
            l_lane[g][r] += mbuf[2048 + ((g << 2) | r) * 64 + l];
            t_lane[g][r] += mbuf[2560 + ((g << 2) | r) * 64 + l];
        }
    }

    // ---- epilogue (wave 0 only) ----
    const float bg2v = bg2[0];
#pragma unroll
    for (int g = 0; g < 2; ++g) {
        float sc[4];
#pragma unroll
        for (int r = 0; r < 4; ++r) {
            float lv = l_lane[g][r], tv = t_lane[g][r];
#pragma unroll
            for (int msk = 1; msk < 16; msk <<= 1) {
                lv += __shfl_xor(lv, msk, 16);
                tv += __shfl_xor(tv, msk, 16);
            }
            int qg = wq + g * 16 + q4 * 4 + r;
            float inv = 1.f / lv;
            if (ln == 0)
                ent[((size_t)b * NH + h) * Nseq + qg] = logf(lv) - tv * inv;
            float logit = glogit[b * Nseq + qg] + bg2v;
            sc[r] = inv / (1.f + __expf(-logit));
        }
#pragma unroll
        for (int nb = 0; nb < 4; ++nb)
#pragma unroll
            for (int r = 0; r < 4; ++r) {
                int qg = wq + g * 16 + q4 * 4 + r;
                AO[(size_t)(b * Nseq + qg) * Dmod + h * DHd + nb * 16 + ln] =
                    f2bf(oacc[g][nb][r] * sc[r]);
            }
    }
}

// ---------------------------------------------------------------------------
extern "C" void kernel_launch(void* const* d_in, const int* in_sizes, int n_in,
                              void* d_out, int out_size, void* d_ws, size_t ws_size,
                              hipStream_t stream)
{
    const float* x   = (const float*)d_in[0];
    const float* Wq  = (const float*)d_in[2];
    const float* bq  = (const float*)d_in[3];
    const float* Wk  = (const float*)d_in[4];
    const float* bk  = (const float*)d_in[5];
    const float* Wv  = (const float*)d_in[6];
    const float* bv  = (const float*)d_in[7];
    const float* Wg1 = (const float*)d_in[8];
    const float* bg1 = (const float*)d_in[9];
    const float* Wg2 = (const float*)d_in[10];
    const float* bg2 = (const float*)d_in[11];
    const float* Wo  = (const float*)d_in[12];
    const float* bo  = (const float*)d_in[13];

    const size_t NE = (size_t)MTOT * Dmod;
    ushortT* p   = (ushortT*)d_ws;
    ushortT* Qw  = p; p += NE;
    ushortT* Kw  = p; p += NE;
    ushortT* Vtw = p; p += NE;       // V transposed: [B,H,64,Nseq]
    ushortT* AO  = p; p += NE;
    ushortT* xb  = p; p += NE;
    ushortT* WtQ = p; p += (size_t)1024 * 1024;
    ushortT* WtK = p; p += (size_t)1024 * 1024;
    ushortT* WtV = p; p += (size_t)1024 * 1024;
    ushortT* WtG = p; p += (size_t)1024 * 1024;
    ushortT* WtO = p; p += (size_t)1024 * 1024;
    float* glogit = (float*)p;       // MTOT floats

    float* out_f = (float*)d_out;
    float* ent_f = out_f + NE;

    prep_kernel<<<dim3(16, 16, 6), 256, 0, stream>>>(Wq, Wk, Wv, Wg1, Wo,
                                                     WtQ, WtK, WtV, WtG, WtO,
                                                     x, xb, glogit);
    gemm_qkvg<<<dim3(16, 24, 4), 256, 0, stream>>>(xb, WtQ, WtK, WtV, WtG,
                                                   bq, bk, bv, bg1, Wg2,
                                                   Qw, Kw, Vtw, glogit);
    attn_mfma<<<dim3(Bsz * NH, Nseq / 32), 128, 0, stream>>>(Qw, Kw, Vtw, glogit,
                                                             bg2, AO, ent_f);
    gemm_out<<<dim3(16, 48), 256, 0, stream>>>(AO, WtO, bo, out_f);
}